// Round 2
// baseline (362.296 us; speedup 1.0000x reference)
//
#include <hip/hip_runtime.h>
#include <hip/hip_cooperative_groups.h>

namespace cg = cooperative_groups;

#define M_DIM 4096
#define N_DIM 4096
#define K_DIM 4096

typedef float f32x4 __attribute__((ext_vector_type(4)));
typedef __bf16 bf16x8 __attribute__((ext_vector_type(8)));

// round-to-nearest-even fp32 -> bf16
__device__ __forceinline__ unsigned short f2b(float f) {
    unsigned int u = __float_as_uint(f);
    u += 0x7fffu + ((u >> 16) & 1u);
    return (unsigned short)(u >> 16);
}

// Arithmetic NVFP4 (e2m1) decode — pure VALU, bit-exact vs the codebook.
__device__ __forceinline__ float nvfp4_decode(int n) {
    unsigned m = (unsigned)n & 7u;
    unsigned e = m >> 1, f = m & 1u;
    unsigned bits = (m >= 2u) ? (((126u + e) << 23) | (f << 22))
                              : (m * 0x3f000000u);   // 0 -> 0.0f, 1 -> 0.5f
    bits |= ((unsigned)n & 8u) << 28;                 // sign
    return __uint_as_float(bits);
}

// ---------------------------------------------------------------------------
// Prep phase body: grid is 256 blocks x 512 threads (the gemm config).
// Block b converts x rows [16b,16b+16) and builds W rows [16b,16b+16).
// ---------------------------------------------------------------------------
__device__ __forceinline__ void prep_body(
        const float* __restrict__ x, unsigned short* __restrict__ xb,
        const int* __restrict__ idx4, const float* __restrict__ sc4,
        const float* __restrict__ gs4, const float* __restrict__ w8,
        const float* __restrict__ s8, const float* __restrict__ w16,
        const int* __restrict__ iperm, unsigned short* __restrict__ W) {
    const int b = blockIdx.x;    // 0..255
    const int t = threadIdx.x;   // 0..511

    // ---- x fp32 -> bf16 ----
#pragma unroll 4
    for (int i = 0; i < 16; ++i) {
        const size_t off = ((size_t)(b * 16 + i) * 512 + t) * 8;
        float4 a0 = *(const float4*)(x + off);
        float4 a1 = *(const float4*)(x + off + 4);
        union { unsigned short h[8]; uint4 u; } o;
        o.h[0] = f2b(a0.x); o.h[1] = f2b(a0.y); o.h[2] = f2b(a0.z); o.h[3] = f2b(a0.w);
        o.h[4] = f2b(a1.x); o.h[5] = f2b(a1.y); o.h[6] = f2b(a1.z); o.h[7] = f2b(a1.w);
        *(uint4*)(xb + off) = o.u;
    }

    // ---- permuted + dequantized W (bf16) ----
    const float gs = gs4[0];
    const float s8v = s8[0];
#pragma unroll 2
    for (int i = 0; i < 16; ++i) {
        const int j = b * 16 + i;
        const int g = iperm[j];
        const int k0 = t * 8;
        union { unsigned short hh[8]; uint4 u; } o;
        if (g < 2048) {
            const float s = sc4[(size_t)g * (K_DIM / 16) + (k0 >> 4)] * gs;
            const int4* ip = (const int4*)(idx4 + (size_t)g * K_DIM + k0);
            int4 v0 = ip[0], v1 = ip[1];
            o.hh[0] = f2b(nvfp4_decode(v0.x) * s);
            o.hh[1] = f2b(nvfp4_decode(v0.y) * s);
            o.hh[2] = f2b(nvfp4_decode(v0.z) * s);
            o.hh[3] = f2b(nvfp4_decode(v0.w) * s);
            o.hh[4] = f2b(nvfp4_decode(v1.x) * s);
            o.hh[5] = f2b(nvfp4_decode(v1.y) * s);
            o.hh[6] = f2b(nvfp4_decode(v1.z) * s);
            o.hh[7] = f2b(nvfp4_decode(v1.w) * s);
        } else if (g < 3072) {
            const float4* wp = (const float4*)(w8 + (size_t)(g - 2048) * K_DIM + k0);
            float4 v0 = wp[0], v1 = wp[1];
            o.hh[0] = f2b(v0.x * s8v); o.hh[1] = f2b(v0.y * s8v);
            o.hh[2] = f2b(v0.z * s8v); o.hh[3] = f2b(v0.w * s8v);
            o.hh[4] = f2b(v1.x * s8v); o.hh[5] = f2b(v1.y * s8v);
            o.hh[6] = f2b(v1.z * s8v); o.hh[7] = f2b(v1.w * s8v);
        } else {
            const float4* wp = (const float4*)(w16 + (size_t)(g - 3072) * K_DIM + k0);
            float4 v0 = wp[0], v1 = wp[1];
            o.hh[0] = f2b(v0.x); o.hh[1] = f2b(v0.y);
            o.hh[2] = f2b(v0.z); o.hh[3] = f2b(v0.w);
            o.hh[4] = f2b(v1.x); o.hh[5] = f2b(v1.y);
            o.hh[6] = f2b(v1.z); o.hh[7] = f2b(v1.w);
        }
        *(uint4*)(W + (size_t)j * K_DIM + k0) = o.u;
    }
}

// ---------------------------------------------------------------------------
// GEMM body: C[M,N] = Xb[M,K] * Wb[N,K]^T + bias
// 256x256 tile, BK=64, 8 waves (2Mx4N), 8-phase counted-vmcnt schedule
// (T3+T4) + st_16x32 LDS swizzle (T2) + setprio (T5).
//
// Round-2 change: A held ENTIRELY in registers (af0+af1, 64 VGPR) across the
// tile; quadrant walk (0,0)->(1,0)->(1,1)->(0,1) so each phase loads at most
// one operand. ds_reads/wave/K-tile: 28 -> 24 (the minimum). Phase 4 has no
// ds_reads -> clean slot for the counted vmcnt.
//   reads per phase:  ph1: A0,B0   ph2: A1   ph3: B1   ph4: -
//   stage slots (unchanged pattern, re-verified free/drain windows):
//     ph1: T1.B0   ph2: T1.A1   ph3: T2.A0   ph4: T2.B1  [vmcnt(4)]
//     ph5: T2.B0   ph6: T2.A1   ph7: T3.A0   ph8: T3.B1  [vmcnt(4)]
//   write-after-read: each staged region's last read is >=1 barrier-pair
//   before the stage issue (A0:ph1<ph3, B1:ph3<ph4, B0:ph1<ph5, A1:ph2<ph6,
//   buf1 A0:ph5<ph7, B1:ph7<ph8). drain-before-first-read: every T+2 chunk
//   is issued in [T.ph3, T+1.ph2] -> drained by T+1-end vmcnt(4); T+3 chunks
//   (ph7/ph8) stay in flight across it -> drained at T+2-end.
// ---------------------------------------------------------------------------
#define GLOAD_LDS16(g, l)                                                     \
    __builtin_amdgcn_global_load_lds(                                         \
        (const __attribute__((address_space(1))) void*)(unsigned long long)(g),\
        (__attribute__((address_space(3))) void*)(unsigned int)(unsigned long long)(l), \
        16, 0, 0)

#define STAGE(p, d, kt, buf) do {                                             \
    const unsigned short* _s = (p) + (size_t)(kt) * 64;                       \
    GLOAD_LDS16(_s,      smem + (buf) * 32768 + (d));                         \
    GLOAD_LDS16(_s + 32, smem + (buf) * 32768 + (d) + 1024);                  \
} while (0)

#define LOADA(AF, buf, qm) do {                                               \
    _Pragma("unroll") for (int mi = 0; mi < 4; ++mi)                          \
        _Pragma("unroll") for (int kk = 0; kk < 2; ++kk)                      \
            AF[mi][kk] = *(const bf16x8*)(rdA + (buf) * 32768 +               \
                                          (((qm) * 8 + mi * 2 + kk) << 10));  \
} while (0)

#define LOADB(buf, qn) do {                                                   \
    _Pragma("unroll") for (int nj = 0; nj < 2; ++nj)                          \
        _Pragma("unroll") for (int kk = 0; kk < 2; ++kk)                      \
            bq[nj][kk] = *(const bf16x8*)(rdB + (buf) * 32768 +               \
                                          (((qn) * 4 + nj * 2 + kk) << 10));  \
} while (0)

#define MMA(AF, qm, qn) do {                                                  \
    _Pragma("unroll") for (int mi = 0; mi < 4; ++mi)                          \
        _Pragma("unroll") for (int nj = 0; nj < 2; ++nj) {                    \
            acc[(qm)*4+mi][(qn)*2+nj] = __builtin_amdgcn_mfma_f32_16x16x32_bf16( \
                AF[mi][0], bq[nj][0], acc[(qm)*4+mi][(qn)*2+nj], 0, 0, 0);    \
            acc[(qm)*4+mi][(qn)*2+nj] = __builtin_amdgcn_mfma_f32_16x16x32_bf16( \
                AF[mi][1], bq[nj][1], acc[(qm)*4+mi][(qn)*2+nj], 0, 0, 0);    \
        }                                                                     \
} while (0)

#define BARRIER __builtin_amdgcn_s_barrier()
#define WAIT_LGKM asm volatile("s_waitcnt lgkmcnt(0)" ::: "memory")
#define WAIT_VM4 asm volatile("s_waitcnt vmcnt(4)" ::: "memory")
#define PRIO1 __builtin_amdgcn_s_setprio(1)
#define PRIO0 __builtin_amdgcn_s_setprio(0)

__device__ __forceinline__ void gemm_body(
        const unsigned short* __restrict__ X, const unsigned short* __restrict__ W,
        const float* __restrict__ bias, float* __restrict__ C) {
    __shared__ __align__(128) unsigned char smem[131072];

    // XCD-aware chunked swizzle: 256 blocks, 8 XCDs, 32 contiguous wgs each
    const int pid = blockIdx.x;
    const int wg = (pid & 7) * 32 + (pid >> 3);
    const int bm = wg >> 4, bn = wg & 15;
    const int m0 = bm * 256, n0 = bn * 256;

    const int tid  = threadIdx.x;
    const int wave = tid >> 6;       // 0..7
    const int lane = tid & 63;
    const int wr   = wave >> 2;      // 0..1  (M half)
    const int wc   = wave & 3;       // 0..3  (N quarter)
    const int l16  = lane & 15;
    const int quad = lane >> 4;

    // ---- staging: per-lane global source (inverse st_16x32 swizzle) ----
    const int srow = lane >> 2;                               // 0..15 within subtile
    const int scol = ((lane & 3) ^ ((lane >> 5) << 1)) << 3;  // elems; lanes>=32 swap 16B pairs

    const unsigned short* pA0 = X + (size_t)(m0 + (wr * 8 + wc) * 16 + srow) * K_DIM + scol;
    const unsigned short* pA1 = pA0 + (size_t)64 * K_DIM;
    const unsigned short* pB0 = W + (size_t)(n0 + (wc * 4 + wr) * 16 + srow) * K_DIM + scol;
    const unsigned short* pB1 = pB0 + (size_t)32 * K_DIM;

    const int dA0 = (((wr * 8 + wc) * 2) << 10) + lane * 16;
    const int dA1 = dA0 + 8192;
    const int dB0 = 65536 + (((wc * 4 + wr) * 2) << 10) + lane * 16;
    const int dB1 = dB0 + 4096;

    // ---- fragment read addressing (swizzled) ----
    const int inner_rd = ((l16 << 6) | (quad << 4)) ^ ((l16 & 8) << 2);
    const unsigned char* rdA = smem + ((wr * 16) << 10) + inner_rd;
    const unsigned char* rdB = smem + 65536 + ((wc * 8) << 10) + inner_rd;

    f32x4 acc[8][4] = {};
    bf16x8 af0[4][2], af1[4][2], bq[2][2];

    // ---- prologue: T0 fully + T1.{A0,B1}; vmcnt(4) keeps T1 chunks in flight
    STAGE(pA0, dA0, 0, 0);
    STAGE(pB0, dB0, 0, 0);
    STAGE(pB1, dB1, 0, 0);
    STAGE(pA1, dA1, 0, 0);
    STAGE(pA0, dA0, 1, 1);
    STAGE(pB1, dB1, 1, 1);
    WAIT_VM4;
    BARRIER;

#pragma unroll 1
    for (int it = 0; it < 32; ++it) {
        const int t1 = 2 * it + 1;
        const int t2 = (2 * it + 2) & 63;
        const int t3 = (2 * it + 3) & 63;

        // ===== K-tile 2*it (buf0) =====
        // phase 1: q(0,0)
        LOADA(af0, 0, 0); LOADB(0, 0);
        STAGE(pB0, dB0, t1, 1);
        BARRIER; WAIT_LGKM;
        PRIO1; MMA(af0, 0, 0); PRIO0;
        BARRIER;
        // phase 2: q(1,0)
        LOADA(af1, 0, 1);
        STAGE(pA1, dA1, t1, 1);
        BARRIER; WAIT_LGKM;
        PRIO1; MMA(af1, 1, 0); PRIO0;
        BARRIER;
        // phase 3: q(1,1)
        LOADB(0, 1);
        STAGE(pA0, dA0, t2, 0);
        BARRIER; WAIT_LGKM;
        PRIO1; MMA(af1, 1, 1); PRIO0;
        BARRIER;
        // phase 4: q(0,1) — no ds_reads
        STAGE(pB1, dB1, t2, 0);
        BARRIER;
        PRIO1; MMA(af0, 0, 1); PRIO0;
        WAIT_VM4;          // all of T1 landed; only T2.{A0,B1} in flight
        BARRIER;

        // ===== K-tile 2*it+1 (buf1) =====
        // phase 5: q(0,0)
        LOADA(af0, 1, 0); LOADB(1, 0);
        STAGE(pB0, dB0, t2, 0);
        BARRIER; WAIT_LGKM;
        PRIO1; MMA(af0, 0, 0); PRIO0;
        BARRIER;
        // phase 6: q(1,0)
        LOADA(af1, 1, 1);
        STAGE(pA1, dA1, t2, 0);
        BARRIER; WAIT_LGKM;
        PRIO1; MMA(af1, 1, 0); PRIO0;
        BARRIER;
        // phase 7: q(1,1)
        LOADB(1, 1);
        STAGE(pA0, dA0, t3, 1);
        BARRIER; WAIT_LGKM;
        PRIO1; MMA(af1, 1, 1); PRIO0;
        BARRIER;
        // phase 8: q(0,1) — no ds_reads
        STAGE(pB1, dB1, t3, 1);
        BARRIER;
        PRIO1; MMA(af0, 0, 1); PRIO0;
        WAIT_VM4;          // all of T2 landed; only T3.{A0,B1} in flight
        BARRIER;
    }

    // ---- epilogue: C/D layout col=lane&15, row=(lane>>4)*4+reg ----
    const int crow0 = m0 + wr * 128 + quad * 4;
    const int ccol0 = n0 + wc * 64 + l16;
    float bv[4];
#pragma unroll
    for (int p = 0; p < 4; ++p) bv[p] = bias[ccol0 + p * 16];
#pragma unroll
    for (int q = 0; q < 8; ++q) {
#pragma unroll
        for (int p = 0; p < 4; ++p) {
            const int col = ccol0 + p * 16;
            const int row = crow0 + q * 16;
#pragma unroll
            for (int r = 0; r < 4; ++r)
                C[(size_t)(row + r) * N_DIM + col] = acc[q][p][r] + bv[p];
        }
    }
}

// ---------------------------------------------------------------------------
// Fused cooperative kernel: prep -> grid sync -> gemm. One dispatch total.
// Grid 256 x 512, 128 KiB LDS -> exactly 1 block/CU on 256 CUs.
// ---------------------------------------------------------------------------
__global__ __launch_bounds__(512, 2) void fused_kernel(
        const float* __restrict__ x, unsigned short* __restrict__ xb,
        const int* __restrict__ idx4, const float* __restrict__ sc4,
        const float* __restrict__ gs4, const float* __restrict__ w8,
        const float* __restrict__ s8, const float* __restrict__ w16,
        const int* __restrict__ iperm, unsigned short* __restrict__ wb,
        const float* __restrict__ bias, float* __restrict__ out) {
    prep_body(x, xb, idx4, sc4, gs4, w8, s8, w16, iperm, wb);
    cg::this_grid().sync();
    gemm_body(xb, wb, bias, out);
}

// Fallback pair (non-cooperative) in case hipLaunchCooperativeKernel fails
// under graph capture.
__global__ __launch_bounds__(512, 2) void prep_kernel(
        const float* __restrict__ x, unsigned short* __restrict__ xb,
        const int* __restrict__ idx4, const float* __restrict__ sc4,
        const float* __restrict__ gs4, const float* __restrict__ w8,
        const float* __restrict__ s8, const float* __restrict__ w16,
        const int* __restrict__ iperm, unsigned short* __restrict__ wb) {
    prep_body(x, xb, idx4, sc4, gs4, w8, s8, w16, iperm, wb);
}

__global__ __launch_bounds__(512, 2) void gemm_kernel(
        const unsigned short* __restrict__ X, const unsigned short* __restrict__ W,
        const float* __restrict__ bias, float* __restrict__ C) {
    gemm_body(X, W, bias, C);
}

// ---------------------------------------------------------------------------
extern "C" void kernel_launch(void* const* d_in, const int* in_sizes, int n_in,
                              void* d_out, int out_size, void* d_ws, size_t ws_size,
                              hipStream_t stream) {
    const float* x            = (const float*)d_in[0];
    const int*   nvfp4_idx    = (const int*)d_in[1];
    const float* nvfp4_scales = (const float*)d_in[2];
    const float* gscale       = (const float*)d_in[3];
    const float* w_fp8        = (const float*)d_in[4];
    const float* fp8_scale    = (const float*)d_in[5];
    const float* w_fp16       = (const float*)d_in[6];
    const float* bias         = (const float*)d_in[7];
    const int*   inv_perm     = (const int*)d_in[8];
    float* out = (float*)d_out;

    unsigned short* xb = (unsigned short*)d_ws;                 // 32 MiB
    unsigned short* wb = xb + (size_t)M_DIM * K_DIM;            // 32 MiB

    void* fargs[] = {(void*)&x, (void*)&xb, (void*)&nvfp4_idx, (void*)&nvfp4_scales,
                     (void*)&gscale, (void*)&w_fp8, (void*)&fp8_scale, (void*)&w_fp16,
                     (void*)&inv_perm, (void*)&wb, (void*)&bias, (void*)&out};
    hipError_t e = hipLaunchCooperativeKernel((const void*)fused_kernel,
                                              dim3(256), dim3(512), fargs, 0, stream);
    if (e != hipSuccess) {
        prep_kernel<<<256, 512, 0, stream>>>(x, xb, nvfp4_idx, nvfp4_scales,
                                             gscale, w_fp8, fp8_scale, w_fp16,
                                             inv_perm, wb);
        gemm_kernel<<<256, 512, 0, stream>>>(xb, wb, bias, out);
    }
}

// Round 3
// 293.929 us; speedup vs baseline: 1.2326x; 1.2326x over previous
//
#include <hip/hip_runtime.h>

#define M_DIM 4096
#define N_DIM 4096
#define K_DIM 4096

typedef float f32x4 __attribute__((ext_vector_type(4)));
typedef __bf16 bf16x8 __attribute__((ext_vector_type(8)));

// round-to-nearest-even fp32 -> bf16
__device__ __forceinline__ unsigned short f2b(float f) {
    unsigned int u = __float_as_uint(f);
    u += 0x7fffu + ((u >> 16) & 1u);
    return (unsigned short)(u >> 16);
}

// Arithmetic NVFP4 (e2m1) decode — pure VALU, bit-exact vs the codebook.
__device__ __forceinline__ float nvfp4_decode(int n) {
    unsigned m = (unsigned)n & 7u;
    unsigned e = m >> 1, f = m & 1u;
    unsigned bits = (m >= 2u) ? (((126u + e) << 23) | (f << 22))
                              : (m * 0x3f000000u);   // 0 -> 0.0f, 1 -> 0.5f
    bits |= ((unsigned)n & 8u) << 28;                 // sign
    return __uint_as_float(bits);
}

// ---------------------------------------------------------------------------
// Prep: separate high-occupancy streaming kernels (round-1 structure, proven
// ~31us total = traffic roofline). Fusion into the 1-block/CU gemm regressed
// prep to ~115us (2 waves/SIMD can't hide HBM latency) — reverted.
// ---------------------------------------------------------------------------
__global__ __launch_bounds__(256) void xconv_kernel(
        const float* __restrict__ x, unsigned short* __restrict__ xb) {
    size_t i = ((size_t)blockIdx.x * 256 + threadIdx.x) * 8;
    float4 a0 = *(const float4*)(x + i);
    float4 a1 = *(const float4*)(x + i + 4);
    union { unsigned short h[8]; uint4 u; } o;
    o.h[0] = f2b(a0.x); o.h[1] = f2b(a0.y); o.h[2] = f2b(a0.z); o.h[3] = f2b(a0.w);
    o.h[4] = f2b(a1.x); o.h[5] = f2b(a1.y); o.h[6] = f2b(a1.z); o.h[7] = f2b(a1.w);
    *(uint4*)(xb + i) = o.u;
}

__global__ __launch_bounds__(256) void wbuild_kernel(
        const int* __restrict__ idx4, const float* __restrict__ sc4,
        const float* __restrict__ gs4, const float* __restrict__ w8,
        const float* __restrict__ s8, const float* __restrict__ w16,
        const int* __restrict__ iperm, unsigned short* __restrict__ W) {
    const int j = blockIdx.x;
    const int t = threadIdx.x;
    const int g = iperm[j];

#pragma unroll
    for (int h = 0; h < 2; ++h) {
        const int k0 = h * 2048 + t * 8;   // 8 elems / thread / half
        union { unsigned short hh[8]; uint4 u; } o;
        if (g < 2048) {
            const float s = sc4[(size_t)g * (K_DIM / 16) + (k0 >> 4)] * gs4[0];
            const int4* ip = (const int4*)(idx4 + (size_t)g * K_DIM + k0);
            int4 v0 = ip[0], v1 = ip[1];
            o.hh[0] = f2b(nvfp4_decode(v0.x) * s);
            o.hh[1] = f2b(nvfp4_decode(v0.y) * s);
            o.hh[2] = f2b(nvfp4_decode(v0.z) * s);
            o.hh[3] = f2b(nvfp4_decode(v0.w) * s);
            o.hh[4] = f2b(nvfp4_decode(v1.x) * s);
            o.hh[5] = f2b(nvfp4_decode(v1.y) * s);
            o.hh[6] = f2b(nvfp4_decode(v1.z) * s);
            o.hh[7] = f2b(nvfp4_decode(v1.w) * s);
        } else if (g < 3072) {
            const float s = s8[0];
            const float4* wp = (const float4*)(w8 + (size_t)(g - 2048) * K_DIM + k0);
            float4 v0 = wp[0], v1 = wp[1];
            o.hh[0] = f2b(v0.x * s); o.hh[1] = f2b(v0.y * s);
            o.hh[2] = f2b(v0.z * s); o.hh[3] = f2b(v0.w * s);
            o.hh[4] = f2b(v1.x * s); o.hh[5] = f2b(v1.y * s);
            o.hh[6] = f2b(v1.z * s); o.hh[7] = f2b(v1.w * s);
        } else {
            const float4* wp = (const float4*)(w16 + (size_t)(g - 3072) * K_DIM + k0);
            float4 v0 = wp[0], v1 = wp[1];
            o.hh[0] = f2b(v0.x); o.hh[1] = f2b(v0.y);
            o.hh[2] = f2b(v0.z); o.hh[3] = f2b(v0.w);
            o.hh[4] = f2b(v1.x); o.hh[5] = f2b(v1.y);
            o.hh[6] = f2b(v1.z); o.hh[7] = f2b(v1.w);
        }
        *(uint4*)(W + (size_t)j * K_DIM + k0) = o.u;
    }
}

// ---------------------------------------------------------------------------
// GEMM: C[M,N] = Xb[M,K] * Wb[N,K]^T + bias
// 256x256 tile, BK=64, 8 waves (2Mx4N), 8-phase counted-vmcnt schedule
// (T3+T4) + st_16x32 LDS swizzle (T2) + setprio (T5).
//
// A held ENTIRELY in registers (af0+af1, 64 VGPR) across the K-tile;
// quadrant walk (0,0)->(1,0)->(1,1)->(0,1) so each phase loads at most one
// operand. ds_reads/wave/K-tile: 24 (the per-wave minimum: A-panel 16KiB +
// B-panel 8KiB). Phase 4 is ds-read-free -> clean slot for the counted vmcnt.
//   reads per phase:  ph1: A0,B0   ph2: A1   ph3: B1   ph4: -
//   stage slots:
//     ph1: T1.B0   ph2: T1.A1   ph3: T2.A0   ph4: T2.B1  [vmcnt(4)]
//     ph5: T2.B0   ph6: T2.A1   ph7: T3.A0   ph8: T3.B1  [vmcnt(4)]
//   write-after-read: each staged region's last read is >=1 barrier-pair
//   before the stage issue (A0:ph1<ph3, B1:ph3<ph4, B0:ph1<ph5, A1:ph2<ph6,
//   buf1 A0:ph5<ph7, B1:ph7<ph8). drain-before-first-read: every T+2 chunk
//   is issued in [T.ph3, T+1.ph2] -> drained by T+1-end vmcnt(4); T+3 chunks
//   (ph7/ph8) stay in flight across it -> drained at T+2-end.
// ---------------------------------------------------------------------------
#define GLOAD_LDS16(g, l)                                                     \
    __builtin_amdgcn_global_load_lds(                                         \
        (const __attribute__((address_space(1))) void*)(unsigned long long)(g),\
        (__attribute__((address_space(3))) void*)(unsigned int)(unsigned long long)(l), \
        16, 0, 0)

#define STAGE(p, d, kt, buf) do {                                             \
    const unsigned short* _s = (p) + (size_t)(kt) * 64;                       \
    GLOAD_LDS16(_s,      smem + (buf) * 32768 + (d));                         \
    GLOAD_LDS16(_s + 32, smem + (buf) * 32768 + (d) + 1024);                  \
} while (0)

#define LOADA(AF, buf, qm) do {                                               \
    _Pragma("unroll") for (int mi = 0; mi < 4; ++mi)                          \
        _Pragma("unroll") for (int kk = 0; kk < 2; ++kk)                      \
            AF[mi][kk] = *(const bf16x8*)(rdA + (buf) * 32768 +               \
                                          (((qm) * 8 + mi * 2 + kk) << 10));  \
} while (0)

#define LOADB(buf, qn) do {                                                   \
    _Pragma("unroll") for (int nj = 0; nj < 2; ++nj)                          \
        _Pragma("unroll") for (int kk = 0; kk < 2; ++kk)                      \
            bq[nj][kk] = *(const bf16x8*)(rdB + (buf) * 32768 +               \
                                          (((qn) * 4 + nj * 2 + kk) << 10));  \
} while (0)

#define MMA(AF, qm, qn) do {                                                  \
    _Pragma("unroll") for (int mi = 0; mi < 4; ++mi)                          \
        _Pragma("unroll") for (int nj = 0; nj < 2; ++nj) {                    \
            acc[(qm)*4+mi][(qn)*2+nj] = __builtin_amdgcn_mfma_f32_16x16x32_bf16( \
                AF[mi][0], bq[nj][0], acc[(qm)*4+mi][(qn)*2+nj], 0, 0, 0);    \
            acc[(qm)*4+mi][(qn)*2+nj] = __builtin_amdgcn_mfma_f32_16x16x32_bf16( \
                AF[mi][1], bq[nj][1], acc[(qm)*4+mi][(qn)*2+nj], 0, 0, 0);    \
        }                                                                     \
} while (0)

#define BARRIER __builtin_amdgcn_s_barrier()
#define WAIT_LGKM asm volatile("s_waitcnt lgkmcnt(0)" ::: "memory")
#define WAIT_VM4 asm volatile("s_waitcnt vmcnt(4)" ::: "memory")
#define PRIO1 __builtin_amdgcn_s_setprio(1)
#define PRIO0 __builtin_amdgcn_s_setprio(0)

__global__ __launch_bounds__(512, 2) void gemm_kernel(
        const unsigned short* __restrict__ X, const unsigned short* __restrict__ W,
        const float* __restrict__ bias, float* __restrict__ C) {
    __shared__ __align__(128) unsigned char smem[131072];

    // XCD-aware chunked swizzle: 256 blocks, 8 XCDs, 32 contiguous wgs each
    const int pid = blockIdx.x;
    const int wg = (pid & 7) * 32 + (pid >> 3);
    const int bm = wg >> 4, bn = wg & 15;
    const int m0 = bm * 256, n0 = bn * 256;

    const int tid  = threadIdx.x;
    const int wave = tid >> 6;       // 0..7
    const int lane = tid & 63;
    const int wr   = wave >> 2;      // 0..1  (M half)
    const int wc   = wave & 3;       // 0..3  (N quarter)
    const int l16  = lane & 15;
    const int quad = lane >> 4;

    // ---- staging: per-lane global source (inverse st_16x32 swizzle) ----
    const int srow = lane >> 2;                               // 0..15 within subtile
    const int scol = ((lane & 3) ^ ((lane >> 5) << 1)) << 3;  // elems; lanes>=32 swap 16B pairs

    const unsigned short* pA0 = X + (size_t)(m0 + (wr * 8 + wc) * 16 + srow) * K_DIM + scol;
    const unsigned short* pA1 = pA0 + (size_t)64 * K_DIM;
    const unsigned short* pB0 = W + (size_t)(n0 + (wc * 4 + wr) * 16 + srow) * K_DIM + scol;
    const unsigned short* pB1 = pB0 + (size_t)32 * K_DIM;

    const int dA0 = (((wr * 8 + wc) * 2) << 10) + lane * 16;
    const int dA1 = dA0 + 8192;
    const int dB0 = 65536 + (((wc * 4 + wr) * 2) << 10) + lane * 16;
    const int dB1 = dB0 + 4096;

    // ---- fragment read addressing (swizzled) ----
    const int inner_rd = ((l16 << 6) | (quad << 4)) ^ ((l16 & 8) << 2);
    const unsigned char* rdA = smem + ((wr * 16) << 10) + inner_rd;
    const unsigned char* rdB = smem + 65536 + ((wc * 8) << 10) + inner_rd;

    f32x4 acc[8][4] = {};
    bf16x8 af0[4][2], af1[4][2], bq[2][2];

    // ---- prologue: T0 fully + T1.{A0,B1}; vmcnt(4) keeps T1 chunks in flight
    STAGE(pA0, dA0, 0, 0);
    STAGE(pB0, dB0, 0, 0);
    STAGE(pB1, dB1, 0, 0);
    STAGE(pA1, dA1, 0, 0);
    STAGE(pA0, dA0, 1, 1);
    STAGE(pB1, dB1, 1, 1);
    WAIT_VM4;
    BARRIER;

#pragma unroll 1
    for (int it = 0; it < 32; ++it) {
        const int t1 = 2 * it + 1;
        const int t2 = (2 * it + 2) & 63;
        const int t3 = (2 * it + 3) & 63;

        // ===== K-tile 2*it (buf0) =====
        // phase 1: q(0,0)
        LOADA(af0, 0, 0); LOADB(0, 0);
        STAGE(pB0, dB0, t1, 1);
        BARRIER; WAIT_LGKM;
        PRIO1; MMA(af0, 0, 0); PRIO0;
        BARRIER;
        // phase 2: q(1,0)
        LOADA(af1, 0, 1);
        STAGE(pA1, dA1, t1, 1);
        BARRIER; WAIT_LGKM;
        PRIO1; MMA(af1, 1, 0); PRIO0;
        BARRIER;
        // phase 3: q(1,1)
        LOADB(0, 1);
        STAGE(pA0, dA0, t2, 0);
        BARRIER; WAIT_LGKM;
        PRIO1; MMA(af1, 1, 1); PRIO0;
        BARRIER;
        // phase 4: q(0,1) — no ds_reads
        STAGE(pB1, dB1, t2, 0);
        BARRIER;
        PRIO1; MMA(af0, 0, 1); PRIO0;
        WAIT_VM4;          // all of T1 landed; only T2.{A0,B1} in flight
        BARRIER;

        // ===== K-tile 2*it+1 (buf1) =====
        // phase 5: q(0,0)
        LOADA(af0, 1, 0); LOADB(1, 0);
        STAGE(pB0, dB0, t2, 0);
        BARRIER; WAIT_LGKM;
        PRIO1; MMA(af0, 0, 0); PRIO0;
        BARRIER;
        // phase 6: q(1,0)
        LOADA(af1, 1, 1);
        STAGE(pA1, dA1, t2, 0);
        BARRIER; WAIT_LGKM;
        PRIO1; MMA(af1, 1, 0); PRIO0;
        BARRIER;
        // phase 7: q(1,1)
        LOADB(1, 1);
        STAGE(pA0, dA0, t3, 1);
        BARRIER; WAIT_LGKM;
        PRIO1; MMA(af1, 1, 1); PRIO0;
        BARRIER;
        // phase 8: q(0,1) — no ds_reads
        STAGE(pB1, dB1, t3, 1);
        BARRIER;
        PRIO1; MMA(af0, 0, 1); PRIO0;
        WAIT_VM4;          // all of T2 landed; only T3.{A0,B1} in flight
        BARRIER;
    }

    // ---- epilogue: C/D layout col=lane&15, row=(lane>>4)*4+reg ----
    const int crow0 = m0 + wr * 128 + quad * 4;
    const int ccol0 = n0 + wc * 64 + l16;
    float bv[4];
#pragma unroll
    for (int p = 0; p < 4; ++p) bv[p] = bias[ccol0 + p * 16];
#pragma unroll
    for (int q = 0; q < 8; ++q) {
#pragma unroll
        for (int p = 0; p < 4; ++p) {
            const int col = ccol0 + p * 16;
            const int row = crow0 + q * 16;
#pragma unroll
            for (int r = 0; r < 4; ++r)
                C[(size_t)(row + r) * N_DIM + col] = acc[q][p][r] + bv[p];
        }
    }
}

// ---------------------------------------------------------------------------
extern "C" void kernel_launch(void* const* d_in, const int* in_sizes, int n_in,
                              void* d_out, int out_size, void* d_ws, size_t ws_size,
                              hipStream_t stream) {
    const float* x            = (const float*)d_in[0];
    const int*   nvfp4_idx    = (const int*)d_in[1];
    const float* nvfp4_scales = (const float*)d_in[2];
    const float* gscale       = (const float*)d_in[3];
    const float* w_fp8        = (const float*)d_in[4];
    const float* fp8_scale    = (const float*)d_in[5];
    const float* w_fp16       = (const float*)d_in[6];
    const float* bias         = (const float*)d_in[7];
    const int*   inv_perm     = (const int*)d_in[8];
    float* out = (float*)d_out;

    unsigned short* xb = (unsigned short*)d_ws;                 // 32 MiB
    unsigned short* wb = xb + (size_t)M_DIM * K_DIM;            // 32 MiB

    xconv_kernel<<<8192, 256, 0, stream>>>(x, xb);
    wbuild_kernel<<<4096, 256, 0, stream>>>(nvfp4_idx, nvfp4_scales, gscale,
                                            w_fp8, fp8_scale, w_fp16,
                                            inv_perm, wb);
    gemm_kernel<<<256, 512, 0, stream>>>(xb, wb, bias, out);
}

// Round 4
// 293.653 us; speedup vs baseline: 1.2338x; 1.0009x over previous
//
#include <hip/hip_runtime.h>

#define M_DIM 4096
#define N_DIM 4096
#define K_DIM 4096

typedef float f32x4 __attribute__((ext_vector_type(4)));
typedef __bf16 bf16x8 __attribute__((ext_vector_type(8)));

// round-to-nearest-even fp32 -> bf16
__device__ __forceinline__ unsigned short f2b(float f) {
    unsigned int u = __float_as_uint(f);
    u += 0x7fffu + ((u >> 16) & 1u);
    return (unsigned short)(u >> 16);
}

// Arithmetic NVFP4 (e2m1) decode — pure VALU, bit-exact vs the codebook.
__device__ __forceinline__ float nvfp4_decode(int n) {
    unsigned m = (unsigned)n & 7u;
    unsigned e = m >> 1, f = m & 1u;
    unsigned bits = (m >= 2u) ? (((126u + e) << 23) | (f << 22))
                              : (m * 0x3f000000u);   // 0 -> 0.0f, 1 -> 0.5f
    bits |= ((unsigned)n & 8u) << 28;                 // sign
    return __uint_as_float(bits);
}

// ---------------------------------------------------------------------------
// Prep: separate high-occupancy streaming kernels (proven ~31us total =
// traffic roofline; fusing into the 1-block/CU gemm regressed to ~115us).
// ---------------------------------------------------------------------------
__global__ __launch_bounds__(256) void xconv_kernel(
        const float* __restrict__ x, unsigned short* __restrict__ xb) {
    size_t i = ((size_t)blockIdx.x * 256 + threadIdx.x) * 8;
    float4 a0 = *(const float4*)(x + i);
    float4 a1 = *(const float4*)(x + i + 4);
    union { unsigned short h[8]; uint4 u; } o;
    o.h[0] = f2b(a0.x); o.h[1] = f2b(a0.y); o.h[2] = f2b(a0.z); o.h[3] = f2b(a0.w);
    o.h[4] = f2b(a1.x); o.h[5] = f2b(a1.y); o.h[6] = f2b(a1.z); o.h[7] = f2b(a1.w);
    *(uint4*)(xb + i) = o.u;
}

__global__ __launch_bounds__(256) void wbuild_kernel(
        const int* __restrict__ idx4, const float* __restrict__ sc4,
        const float* __restrict__ gs4, const float* __restrict__ w8,
        const float* __restrict__ s8, const float* __restrict__ w16,
        const int* __restrict__ iperm, unsigned short* __restrict__ W) {
    const int j = blockIdx.x;
    const int t = threadIdx.x;
    const int g = iperm[j];

#pragma unroll
    for (int h = 0; h < 2; ++h) {
        const int k0 = h * 2048 + t * 8;   // 8 elems / thread / half
        union { unsigned short hh[8]; uint4 u; } o;
        if (g < 2048) {
            const float s = sc4[(size_t)g * (K_DIM / 16) + (k0 >> 4)] * gs4[0];
            const int4* ip = (const int4*)(idx4 + (size_t)g * K_DIM + k0);
            int4 v0 = ip[0], v1 = ip[1];
            o.hh[0] = f2b(nvfp4_decode(v0.x) * s);
            o.hh[1] = f2b(nvfp4_decode(v0.y) * s);
            o.hh[2] = f2b(nvfp4_decode(v0.z) * s);
            o.hh[3] = f2b(nvfp4_decode(v0.w) * s);
            o.hh[4] = f2b(nvfp4_decode(v1.x) * s);
            o.hh[5] = f2b(nvfp4_decode(v1.y) * s);
            o.hh[6] = f2b(nvfp4_decode(v1.z) * s);
            o.hh[7] = f2b(nvfp4_decode(v1.w) * s);
        } else if (g < 3072) {
            const float s = s8[0];
            const float4* wp = (const float4*)(w8 + (size_t)(g - 2048) * K_DIM + k0);
            float4 v0 = wp[0], v1 = wp[1];
            o.hh[0] = f2b(v0.x * s); o.hh[1] = f2b(v0.y * s);
            o.hh[2] = f2b(v0.z * s); o.hh[3] = f2b(v0.w * s);
            o.hh[4] = f2b(v1.x * s); o.hh[5] = f2b(v1.y * s);
            o.hh[6] = f2b(v1.z * s); o.hh[7] = f2b(v1.w * s);
        } else {
            const float4* wp = (const float4*)(w16 + (size_t)(g - 3072) * K_DIM + k0);
            float4 v0 = wp[0], v1 = wp[1];
            o.hh[0] = f2b(v0.x); o.hh[1] = f2b(v0.y);
            o.hh[2] = f2b(v0.z); o.hh[3] = f2b(v0.w);
            o.hh[4] = f2b(v1.x); o.hh[5] = f2b(v1.y);
            o.hh[6] = f2b(v1.z); o.hh[7] = f2b(v1.w);
        }
        *(uint4*)(W + (size_t)j * K_DIM + k0) = o.u;
    }
}

// ---------------------------------------------------------------------------
// GEMM: C[M,N] = Xb[M,K] * Wb[N,K]^T + bias
// 256x256 tile, BK=64, 8 waves (2Mx4N), st_16x32 LDS swizzle (T2),
// setprio (T5), PURE double-buffer with ONE barrier + ONE vmcnt per K-tile.
//
// R4 change (vs R3's 8-phase lockstep): R3 paid each phase's LDS drain as
// matrix-pipe idle (reads issued only after the previous phase's MFMAs had
// drained; lgkmcnt(0) full-stop; 8 barriers/K-tile). Since all of tile T+1
// is staged into buf^1 (never the live buffer), intra-tile barriers are
// unnecessary: per K-tile we issue 8 gloads (T+1) + all 20 ds_reads up
// front, let the COMPILER emit counted lgkmcnt per dependency (m97: hipcc
// does this fine-grained), reload B1 mid-tile (overlaps q10's MFMA), and
// end with vmcnt(0)+barrier. vmcnt(0) is harmless here: the stages were
// issued a full tile (~2500 cyc) earlier >> HBM latency (~900 cyc).
//
// Race armor: the vmcnt asm's "memory" clobber stops ds_reads hoisting
// above it; sched_barrier(0) after each s_barrier stops next-tile ds_reads
// (which read subtiles staged by OTHER waves) crossing the barrier.
//
// Quadrant order q00,q10 (B0) then q11,q01 (B1): af0 live whole tile,
// af1 dies after q11, bq reloaded once -> same frag regs as R3 (~124 VGPR,
// keeps 2 waves/SIMD with 128 AGPR acc).
// ---------------------------------------------------------------------------
#define GLOAD_LDS16(g, l)                                                     \
    __builtin_amdgcn_global_load_lds(                                         \
        (const __attribute__((address_space(1))) void*)(unsigned long long)(g),\
        (__attribute__((address_space(3))) void*)(unsigned int)(unsigned long long)(l), \
        16, 0, 0)

#define STAGE(p, d, kt, buf) do {                                             \
    const unsigned short* _s = (p) + (size_t)(kt) * 64;                       \
    GLOAD_LDS16(_s,      smem + (buf) * 32768 + (d));                         \
    GLOAD_LDS16(_s + 32, smem + (buf) * 32768 + (d) + 1024);                  \
} while (0)

#define LOADA(AF, buf, qm) do {                                               \
    _Pragma("unroll") for (int mi = 0; mi < 4; ++mi)                          \
        _Pragma("unroll") for (int kk = 0; kk < 2; ++kk)                      \
            AF[mi][kk] = *(const bf16x8*)(rdA + (buf) * 32768 +               \
                                          (((qm) * 8 + mi * 2 + kk) << 10));  \
} while (0)

#define LOADB(buf, qn) do {                                                   \
    _Pragma("unroll") for (int nj = 0; nj < 2; ++nj)                          \
        _Pragma("unroll") for (int kk = 0; kk < 2; ++kk)                      \
            bq[nj][kk] = *(const bf16x8*)(rdB + (buf) * 32768 +               \
                                          (((qn) * 4 + nj * 2 + kk) << 10));  \
} while (0)

#define MMA(AF, qm, qn) do {                                                  \
    _Pragma("unroll") for (int mi = 0; mi < 4; ++mi)                          \
        _Pragma("unroll") for (int nj = 0; nj < 2; ++nj) {                    \
            acc[(qm)*4+mi][(qn)*2+nj] = __builtin_amdgcn_mfma_f32_16x16x32_bf16( \
                AF[mi][0], bq[nj][0], acc[(qm)*4+mi][(qn)*2+nj], 0, 0, 0);    \
            acc[(qm)*4+mi][(qn)*2+nj] = __builtin_amdgcn_mfma_f32_16x16x32_bf16( \
                AF[mi][1], bq[nj][1], acc[(qm)*4+mi][(qn)*2+nj], 0, 0, 0);    \
        }                                                                     \
} while (0)

#define BARRIER __builtin_amdgcn_s_barrier()
#define WAIT_VM0 asm volatile("s_waitcnt vmcnt(0)" ::: "memory")
#define SCHED_FENCE __builtin_amdgcn_sched_barrier(0)
#define PRIO1 __builtin_amdgcn_s_setprio(1)
#define PRIO0 __builtin_amdgcn_s_setprio(0)

// One K-tile: stage T+1 into buf^1, compute over buf, swap.
#define KTILE(buf, tn) do {                                                   \
    STAGE(pA0, dA0, (tn), (buf) ^ 1);                                         \
    STAGE(pB0, dB0, (tn), (buf) ^ 1);                                         \
    STAGE(pA1, dA1, (tn), (buf) ^ 1);                                         \
    STAGE(pB1, dB1, (tn), (buf) ^ 1);                                         \
    LOADB((buf), 0);                                                          \
    LOADA(af0, (buf), 0);                                                     \
    LOADA(af1, (buf), 1);                                                     \
    PRIO1; MMA(af0, 0, 0); PRIO0;                                             \
    PRIO1; MMA(af1, 1, 0); PRIO0;                                             \
    LOADB((buf), 1);                                                          \
    PRIO1; MMA(af1, 1, 1); PRIO0;                                             \
    PRIO1; MMA(af0, 0, 1); PRIO0;                                             \
    WAIT_VM0;                                                                 \
    BARRIER;                                                                  \
    SCHED_FENCE;                                                              \
} while (0)

__global__ __launch_bounds__(512, 2) void gemm_kernel(
        const unsigned short* __restrict__ X, const unsigned short* __restrict__ W,
        const float* __restrict__ bias, float* __restrict__ C) {
    __shared__ __align__(128) unsigned char smem[131072];

    // XCD-aware chunked swizzle: 256 blocks, 8 XCDs, 32 contiguous wgs each
    const int pid = blockIdx.x;
    const int wg = (pid & 7) * 32 + (pid >> 3);
    const int bm = wg >> 4, bn = wg & 15;
    const int m0 = bm * 256, n0 = bn * 256;

    const int tid  = threadIdx.x;
    const int wave = tid >> 6;       // 0..7
    const int lane = tid & 63;
    const int wr   = wave >> 2;      // 0..1  (M half)
    const int wc   = wave & 3;       // 0..3  (N quarter)
    const int l16  = lane & 15;
    const int quad = lane >> 4;

    // ---- staging: per-lane global source (inverse st_16x32 swizzle) ----
    const int srow = lane >> 2;                               // 0..15 within subtile
    const int scol = ((lane & 3) ^ ((lane >> 5) << 1)) << 3;  // elems; lanes>=32 swap 16B pairs

    const unsigned short* pA0 = X + (size_t)(m0 + (wr * 8 + wc) * 16 + srow) * K_DIM + scol;
    const unsigned short* pA1 = pA0 + (size_t)64 * K_DIM;
    const unsigned short* pB0 = W + (size_t)(n0 + (wc * 4 + wr) * 16 + srow) * K_DIM + scol;
    const unsigned short* pB1 = pB0 + (size_t)32 * K_DIM;

    const int dA0 = (((wr * 8 + wc) * 2) << 10) + lane * 16;
    const int dA1 = dA0 + 8192;
    const int dB0 = 65536 + (((wc * 4 + wr) * 2) << 10) + lane * 16;
    const int dB1 = dB0 + 4096;

    // ---- fragment read addressing (swizzled) ----
    const int inner_rd = ((l16 << 6) | (quad << 4)) ^ ((l16 & 8) << 2);
    const unsigned char* rdA = smem + ((wr * 16) << 10) + inner_rd;
    const unsigned char* rdB = smem + 65536 + ((wc * 8) << 10) + inner_rd;

    f32x4 acc[8][4] = {};
    bf16x8 af0[4][2], af1[4][2], bq[2][2];

    // ---- prologue: stage T0 into buf0, drain, sync ----
    STAGE(pA0, dA0, 0, 0);
    STAGE(pB0, dB0, 0, 0);
    STAGE(pA1, dA1, 0, 0);
    STAGE(pB1, dB1, 0, 0);
    WAIT_VM0;
    BARRIER;
    SCHED_FENCE;

#pragma unroll 1
    for (int it2 = 0; it2 < 32; ++it2) {
        const int ta = 2 * it2 + 1;          // tile staged during even tile
        const int tb = (2 * it2 + 2) & 63;   // tile staged during odd tile (wraps: dead)
        KTILE(0, ta);
        KTILE(1, tb);
    }

    // ---- epilogue: C/D layout col=lane&15, row=(lane>>4)*4+reg ----
    const int crow0 = m0 + wr * 128 + quad * 4;
    const int ccol0 = n0 + wc * 64 + l16;
    float bv[4];
#pragma unroll
    for (int p = 0; p < 4; ++p) bv[p] = bias[ccol0 + p * 16];
#pragma unroll
    for (int q = 0; q < 8; ++q) {
#pragma unroll
        for (int p = 0; p < 4; ++p) {
            const int col = ccol0 + p * 16;
            const int row = crow0 + q * 16;
#pragma unroll
            for (int r = 0; r < 4; ++r)
                C[(size_t)(row + r) * N_DIM + col] = acc[q][p][r] + bv[p];
        }
    }
}

// ---------------------------------------------------------------------------
extern "C" void kernel_launch(void* const* d_in, const int* in_sizes, int n_in,
                              void* d_out, int out_size, void* d_ws, size_t ws_size,
                              hipStream_t stream) {
    const float* x            = (const float*)d_in[0];
    const int*   nvfp4_idx    = (const int*)d_in[1];
    const float* nvfp4_scales = (const float*)d_in[2];
    const float* gscale       = (const float*)d_in[3];
    const float* w_fp8        = (const float*)d_in[4];
    const float* fp8_scale    = (const float*)d_in[5];
    const float* w_fp16       = (const float*)d_in[6];
    const float* bias         = (const float*)d_in[7];
    const int*   inv_perm     = (const int*)d_in[8];
    float* out = (float*)d_out;

    unsigned short* xb = (unsigned short*)d_ws;                 // 32 MiB
    unsigned short* wb = xb + (size_t)M_DIM * K_DIM;            // 32 MiB

    xconv_kernel<<<8192, 256, 0, stream>>>(x, xb);
    wbuild_kernel<<<4096, 256, 0, stream>>>(nvfp4_idx, nvfp4_scales, gscale,
                                            w_fp8, fp8_scale, w_fp16,
                                            inv_perm, wb);
    gemm_kernel<<<256, 512, 0, stream>>>(xb, wb, bias, out);
}